// Round 1
// baseline (231.337 us; speedup 1.0000x reference)
//
#include <hip/hip_runtime.h>
#include <math.h>

#define NROWS 12288      // 4096 features + 8192 queue
#define NFEAT 4096
#define DDIM  256
#define KDIM  1000
#define KPAD  1024
#define EPS_INV 20.0f    // 1/0.05

// workspace layout
static const size_t OFF_E    = 0;                          // 12288*1000 f32 = 49,152,000 B
static const size_t OFF_S    = 49152000;                   // 3 x 1024 f64 accumulators
static const size_t OFF_FINV = OFF_S + 3 * 1024 * 8;       // 12288 f32
static const size_t OFF_RINV = OFF_FINV + 12288 * 4;       // 256 f32

__device__ inline float waveReduceSum(float v) {
    #pragma unroll
    for (int m = 32; m >= 1; m >>= 1) v += __shfl_xor(v, m, 64);
    return v;
}

// ---------------------------------------------------------------------------
// Kernel 0: row norms. Blocks [0,12288): feats/queue rows (256 elems).
//           Blocks [12288,12544): head rows (1000 elems).
__global__ __launch_bounds__(256)
void norms_k(const float* __restrict__ feats, const float* __restrict__ queue,
             const float* __restrict__ head, float* __restrict__ finv,
             float* __restrict__ rinv) {
    __shared__ double red[256];
    int tid = threadIdx.x, b = blockIdx.x;
    double s = 0.0;
    if (b < NROWS) {
        const float* row = (b < NFEAT) ? feats + (size_t)b * DDIM
                                       : queue + (size_t)(b - NFEAT) * DDIM;
        float v = row[tid];
        s = (double)v * (double)v;
    } else {
        int d = b - NROWS;
        const float* row = head + (size_t)d * KDIM;
        for (int k = tid; k < KDIM; k += 256) { float v = row[k]; s += (double)v * (double)v; }
    }
    red[tid] = s; __syncthreads();
    for (int off = 128; off > 0; off >>= 1) {
        if (tid < off) red[tid] += red[tid + off];
        __syncthreads();
    }
    if (tid == 0) {
        double inv = 1.0 / fmax(sqrt(red[0]), 1e-12);
        if (b < NROWS) finv[b] = (float)inv; else rinv[b - NROWS] = (float)inv;
    }
}

// ---------------------------------------------------------------------------
// Kernel 1: L = norm(feats) @ norm(head); E = exp(L*20); S0[k] += colsum(E).
// BM=64, BN=64, BK=16, 256 threads, 4x4 per thread.
__global__ __launch_bounds__(256)
void gemm_exp_k(const float* __restrict__ feats, const float* __restrict__ queue,
                const float* __restrict__ head, const float* __restrict__ finv,
                const float* __restrict__ rinv, float* __restrict__ E,
                double* __restrict__ S0) {
    __shared__ float As[16][64];   // [k][m]
    __shared__ float Bs[16][64];   // [k][n]
    __shared__ float cs[16][64];   // column-partial reduce
    int tid = threadIdx.x;
    int bx = blockIdx.x;           // col tile 0..15
    int by = blockIdx.y;           // row tile 0..191
    int tm = tid >> 4, tn = tid & 15;
    int row0 = by * 64, col0 = bx * 64;

    int arow = tid >> 2, aseg = tid & 3;
    int grA = row0 + arow;
    const float* aptr = (grA < NFEAT) ? (feats + (size_t)grA * DDIM)
                                      : (queue + (size_t)(grA - NFEAT) * DDIM);
    int brow = tid >> 4;
    int bcol = (tid & 15) * 4;
    int gn = col0 + bcol;

    float acc[4][4] = {};
    for (int kt = 0; kt < DDIM; kt += 16) {
        float4 av = *(const float4*)(aptr + kt + aseg * 4);
        float4 bv = make_float4(0.f, 0.f, 0.f, 0.f);
        if (gn < KDIM) bv = *(const float4*)(head + (size_t)(kt + brow) * KDIM + gn);
        float rv = rinv[kt + brow];
        bv.x *= rv; bv.y *= rv; bv.z *= rv; bv.w *= rv;
        __syncthreads();
        As[aseg * 4 + 0][arow] = av.x;
        As[aseg * 4 + 1][arow] = av.y;
        As[aseg * 4 + 2][arow] = av.z;
        As[aseg * 4 + 3][arow] = av.w;
        *(float4*)&Bs[brow][bcol] = bv;
        __syncthreads();
        #pragma unroll
        for (int kk = 0; kk < 16; ++kk) {
            float4 a = *(const float4*)&As[kk][tm * 4];
            float4 b = *(const float4*)&Bs[kk][tn * 4];
            acc[0][0] += a.x * b.x; acc[0][1] += a.x * b.y; acc[0][2] += a.x * b.z; acc[0][3] += a.x * b.w;
            acc[1][0] += a.y * b.x; acc[1][1] += a.y * b.y; acc[1][2] += a.y * b.z; acc[1][3] += a.y * b.w;
            acc[2][0] += a.z * b.x; acc[2][1] += a.z * b.y; acc[2][2] += a.z * b.z; acc[2][3] += a.z * b.w;
            acc[3][0] += a.w * b.x; acc[3][1] += a.w * b.y; acc[3][2] += a.w * b.z; acc[3][3] += a.w * b.w;
        }
    }
    // epilogue: normalize by feat row norm, exp, store E, column partials
    float colp[4] = {0.f, 0.f, 0.f, 0.f};
    int gc0 = col0 + tn * 4;
    #pragma unroll
    for (int i = 0; i < 4; ++i) {
        int grow = row0 + tm * 4 + i;
        float f20 = finv[grow] * EPS_INV;
        float4 ev;
        ev.x = expf(acc[i][0] * f20);
        ev.y = expf(acc[i][1] * f20);
        ev.z = expf(acc[i][2] * f20);
        ev.w = expf(acc[i][3] * f20);
        if (gc0 < KDIM) *(float4*)&E[(size_t)grow * KDIM + gc0] = ev;
        colp[0] += ev.x; colp[1] += ev.y; colp[2] += ev.z; colp[3] += ev.w;
    }
    *(float4*)&cs[tm][tn * 4] = make_float4(colp[0], colp[1], colp[2], colp[3]);
    __syncthreads();
    if (tid < 64) {
        float s = 0.f;
        #pragma unroll
        for (int t = 0; t < 16; ++t) s += cs[t][tid];
        int gc = col0 + tid;
        if (gc < KDIM) atomicAdd(&S0[gc], (double)s);
    }
}

// ---------------------------------------------------------------------------
// Kernel 2: given Sin (col sums), r[k] = 1/(1000*Sin[k]); per row b:
//   c[b] = 1/(12288 * sum_k E[b,k]*r[k]); accumulate Sout[k] += E[b,k]*c[b].
// One wave per 4 rows, 16 rows per block.
__global__ __launch_bounds__(256)
void rowpass_k(const float* __restrict__ E, const double* __restrict__ Sin,
               double* __restrict__ Sout) {
    __shared__ float rlds[KPAD];
    __shared__ double colacc[KDIM];
    int tid = threadIdx.x;
    for (int k = tid; k < KPAD; k += 256)
        rlds[k] = (k < KDIM) ? (float)(1.0 / (1000.0 * Sin[k])) : 0.0f;
    __syncthreads();
    int wave = tid >> 6, lane = tid & 63;
    int rowbase = blockIdx.x * 16 + wave * 4;
    double cacc[16];
    #pragma unroll
    for (int i = 0; i < 16; ++i) cacc[i] = 0.0;

    for (int r = 0; r < 4; ++r) {
        const float* erow = E + (size_t)(rowbase + r) * KDIM;
        float4 ev[4];
        float part = 0.f;
        #pragma unroll
        for (int i = 0; i < 4; ++i) {
            int k = 4 * lane + 256 * i;
            if (k < KDIM) {
                ev[i] = *(const float4*)(erow + k);
                part += ev[i].x * rlds[k] + ev[i].y * rlds[k + 1]
                      + ev[i].z * rlds[k + 2] + ev[i].w * rlds[k + 3];
            }
        }
        float rowsum = waveReduceSum(part);
        float c = 1.0f / (12288.0f * rowsum);
        #pragma unroll
        for (int i = 0; i < 4; ++i) {
            int k = 4 * lane + 256 * i;
            if (k < KDIM) {
                cacc[i * 4 + 0] += (double)(ev[i].x * c);
                cacc[i * 4 + 1] += (double)(ev[i].y * c);
                cacc[i * 4 + 2] += (double)(ev[i].z * c);
                cacc[i * 4 + 3] += (double)(ev[i].w * c);
            }
        }
    }
    // combine 4 waves into LDS (round-robin, no LDS atomics needed)
    for (int w = 0; w < 4; ++w) {
        if (wave == w) {
            #pragma unroll
            for (int i = 0; i < 4; ++i) {
                int k = 4 * lane + 256 * i;
                if (k < KDIM) {
                    if (w == 0) {
                        colacc[k + 0] = cacc[i * 4 + 0];
                        colacc[k + 1] = cacc[i * 4 + 1];
                        colacc[k + 2] = cacc[i * 4 + 2];
                        colacc[k + 3] = cacc[i * 4 + 3];
                    } else {
                        colacc[k + 0] += cacc[i * 4 + 0];
                        colacc[k + 1] += cacc[i * 4 + 1];
                        colacc[k + 2] += cacc[i * 4 + 2];
                        colacc[k + 3] += cacc[i * 4 + 3];
                    }
                }
            }
        }
        __syncthreads();
    }
    for (int k = tid; k < KDIM; k += 256)
        atomicAdd(&Sout[k], colacc[k]);
}

// ---------------------------------------------------------------------------
// Kernel 3: output. r_c[k] = 1/(1000*S2[k]); out[b,:] = E[b,:]*r_c / sum.
// Only rows b < 4096.
__global__ __launch_bounds__(256)
void out_k(const float* __restrict__ E, const double* __restrict__ S2,
           float* __restrict__ out) {
    __shared__ float rlds[KPAD];
    int tid = threadIdx.x;
    for (int k = tid; k < KPAD; k += 256)
        rlds[k] = (k < KDIM) ? (float)(1.0 / (1000.0 * S2[k])) : 0.0f;
    __syncthreads();
    int wave = tid >> 6, lane = tid & 63;
    int rowbase = blockIdx.x * 16 + wave * 4;
    for (int r = 0; r < 4; ++r) {
        const float* erow = E + (size_t)(rowbase + r) * KDIM;
        float* orow = out + (size_t)(rowbase + r) * KDIM;
        float4 wv[4];
        float part = 0.f;
        #pragma unroll
        for (int i = 0; i < 4; ++i) {
            int k = 4 * lane + 256 * i;
            if (k < KDIM) {
                float4 ev = *(const float4*)(erow + k);
                wv[i].x = ev.x * rlds[k];
                wv[i].y = ev.y * rlds[k + 1];
                wv[i].z = ev.z * rlds[k + 2];
                wv[i].w = ev.w * rlds[k + 3];
                part += wv[i].x + wv[i].y + wv[i].z + wv[i].w;
            }
        }
        float s = waveReduceSum(part);
        float inv = 1.0f / s;
        #pragma unroll
        for (int i = 0; i < 4; ++i) {
            int k = 4 * lane + 256 * i;
            if (k < KDIM) {
                float4 ov;
                ov.x = wv[i].x * inv; ov.y = wv[i].y * inv;
                ov.z = wv[i].z * inv; ov.w = wv[i].w * inv;
                *(float4*)(orow + k) = ov;
            }
        }
    }
}

// ---------------------------------------------------------------------------
extern "C" void kernel_launch(void* const* d_in, const int* in_sizes, int n_in,
                              void* d_out, int out_size, void* d_ws, size_t ws_size,
                              hipStream_t stream) {
    (void)in_sizes; (void)n_in; (void)out_size; (void)ws_size;
    const float* feats = (const float*)d_in[0];   // [4096,256]
    const float* head  = (const float*)d_in[1];   // [256,1000]
    const float* queue = (const float*)d_in[2];   // [8192,256]
    float* out = (float*)d_out;                   // [4096,1000]

    char* ws = (char*)d_ws;
    float*  E    = (float*)(ws + OFF_E);
    double* S0   = (double*)(ws + OFF_S);
    double* S1   = S0 + 1024;
    double* S2   = S0 + 2048;
    float*  finv = (float*)(ws + OFF_FINV);
    float*  rinv = (float*)(ws + OFF_RINV);

    hipMemsetAsync(ws + OFF_S, 0, 3 * 1024 * sizeof(double), stream);
    norms_k<<<NROWS + DDIM, 256, 0, stream>>>(feats, queue, head, finv, rinv);
    gemm_exp_k<<<dim3(16, 192), 256, 0, stream>>>(feats, queue, head, finv, rinv, E, S0);
    rowpass_k<<<NROWS / 16, 256, 0, stream>>>(E, S0, S1);
    rowpass_k<<<NROWS / 16, 256, 0, stream>>>(E, S1, S2);
    out_k<<<NFEAT / 16, 256, 0, stream>>>(E, S2, out);
}

// Round 2
// 170.907 us; speedup vs baseline: 1.3536x; 1.3536x over previous
//
#include <hip/hip_runtime.h>
#include <math.h>

typedef _Float16 f16;
typedef _Float16 f16x8 __attribute__((ext_vector_type(8)));
typedef _Float16 f16x4 __attribute__((ext_vector_type(4)));
typedef float f32x4 __attribute__((ext_vector_type(4)));

#define NROWS 12288
#define NFEAT 4096
#define DDIM  256
#define KDIM  1000
#define KPAD  1024

// workspace layout (bytes)
static const size_t OFF_A16  = 0;           // 12288*256 f16 = 6,291,456
static const size_t OFF_BF   = 6291456;     // 1024*256 f16  =   524,288
static const size_t OFF_E16  = 6815744;     // 12288*1024 f16= 25,165,824
static const size_t OFF_S    = 31981568;    // 3*1024 f32
static const size_t OFF_RINV = 31993856;    // 256 f32

__device__ inline float wsum(float v) {
#pragma unroll
    for (int m = 32; m >= 1; m >>= 1) v += __shfl_xor(v, m, 64);
    return v;
}

// ---------------------------------------------------------------------------
// normalize feats/queue rows, write A16 (f16, finv folded in). 4 rows/block.
__global__ __launch_bounds__(256)
void norm_feats_k(const float* __restrict__ feats, const float* __restrict__ queue,
                  f16* __restrict__ A16) {
    int tid = threadIdx.x, wave = tid >> 6, lane = tid & 63;
    int row = blockIdx.x * 4 + wave;
    const float* src = (row < NFEAT) ? feats + (size_t)row * DDIM
                                     : queue + (size_t)(row - NFEAT) * DDIM;
    float4 v = *(const float4*)(src + lane * 4);
    float s = v.x * v.x + v.y * v.y + v.z * v.z + v.w * v.w;
    s = wsum(s);
    float inv = 1.0f / sqrtf(fmaxf(s, 1e-24f));
    f16x4 o = { (f16)(v.x * inv), (f16)(v.y * inv), (f16)(v.z * inv), (f16)(v.w * inv) };
    *(f16x4*)(A16 + (size_t)row * DDIM + lane * 4) = o;
}

// head row norms (axis=1, length 1000). one block per k.
__global__ __launch_bounds__(256)
void rinv_k(const float* __restrict__ head, float* __restrict__ rinv) {
    __shared__ float red[4];
    int tid = threadIdx.x, k = blockIdx.x;
    float s = 0.f;
    for (int n = tid; n < KDIM; n += 256) { float v = head[(size_t)k * KDIM + n]; s += v * v; }
    s = wsum(s);
    if ((tid & 63) == 0) red[tid >> 6] = s;
    __syncthreads();
    if (tid == 0) rinv[k] = 1.0f / sqrtf(fmaxf(red[0] + red[1] + red[2] + red[3], 1e-24f));
}

// Bf[n][k] = f16(head[k][n] * rinv[k])  (transposed, k-contiguous)
__global__ __launch_bounds__(256)
void cvt_head_k(const float* __restrict__ head, const float* __restrict__ rinv,
                f16* __restrict__ Bf) {
    int n = blockIdx.x * 256 + threadIdx.x;
    int k0 = blockIdx.y * 16;
    if (n >= KDIM) return;
    f16 tmp[16];
#pragma unroll
    for (int i = 0; i < 16; ++i)
        tmp[i] = (f16)(head[(size_t)(k0 + i) * KDIM + n] * rinv[k0 + i]);
    f16* dst = Bf + (size_t)n * DDIM + k0;
    *(uint4*)(dst)     = *(const uint4*)(tmp);
    *(uint4*)(dst + 8) = *(const uint4*)(tmp + 8);
}

// ---------------------------------------------------------------------------
// MFMA GEMM + exp + colsum partials + f16 E store.
// 128x128 tile, 4 waves (2x2 of 64x64), direct global fragment loads.
__global__ __launch_bounds__(256, 2)
void gemm_exp_k(const f16* __restrict__ A16, const f16* __restrict__ Bf,
                f16* __restrict__ E16, float* __restrict__ S0) {
    __shared__ f16 Es[128][136];     // stride 272 B: 16B-aligned rows, modest conflicts
    int tid = threadIdx.x;
    int wave = tid >> 6, lane = tid & 63;
    int lm = lane & 15, q = lane >> 4;
    int row0 = blockIdx.y * 128, col0 = blockIdx.x * 128;
    int wm = (wave >> 1) * 64, wn = (wave & 1) * 64;
    const f16* Ab = A16 + (size_t)(row0 + wm + lm) * DDIM + q * 8;
    const f16* Bb = Bf  + (size_t)(col0 + wn + lm) * DDIM + q * 8;

    f32x4 acc[4][4];
#pragma unroll
    for (int i = 0; i < 4; ++i)
#pragma unroll
        for (int j = 0; j < 4; ++j) acc[i][j] = (f32x4){0.f, 0.f, 0.f, 0.f};

#pragma unroll
    for (int kt = 0; kt < DDIM; kt += 32) {
        f16x8 a[4], b[4];
#pragma unroll
        for (int ms = 0; ms < 4; ++ms) a[ms] = *(const f16x8*)(Ab + (size_t)ms * 16 * DDIM + kt);
#pragma unroll
        for (int ns = 0; ns < 4; ++ns) b[ns] = *(const f16x8*)(Bb + (size_t)ns * 16 * DDIM + kt);
#pragma unroll
        for (int ms = 0; ms < 4; ++ms)
#pragma unroll
            for (int ns = 0; ns < 4; ++ns)
                acc[ms][ns] = __builtin_amdgcn_mfma_f32_16x16x32_f16(a[ms], b[ns], acc[ms][ns], 0, 0, 0);
    }

    // epilogue: e = exp(20*logit), masked past col 999; colsums in registers
    float colp[4] = {0.f, 0.f, 0.f, 0.f};
#pragma unroll
    for (int ms = 0; ms < 4; ++ms) {
#pragma unroll
        for (int ns = 0; ns < 4; ++ns) {
            int gc = col0 + wn + ns * 16 + lm;
            bool ok = gc < KDIM;
#pragma unroll
            for (int r = 0; r < 4; ++r) {
                float e = ok ? __expf(acc[ms][ns][r] * 20.0f) : 0.0f;
                colp[ns] += e;
                Es[wm + ms * 16 + q * 4 + r][wn + ns * 16 + lm] = (f16)e;
            }
        }
    }
#pragma unroll
    for (int ns = 0; ns < 4; ++ns) {   // reduce over quads (m), then atomics
        float v = colp[ns];
        v += __shfl_xor(v, 16, 64);
        v += __shfl_xor(v, 32, 64);
        if (lane < 16) atomicAdd(&S0[col0 + wn + ns * 16 + lane], v);
    }
    __syncthreads();
    // coalesced f16 store of the block's 128x128 tile
    int r = tid >> 1, half = tid & 1;
    const f16* src = &Es[r][half * 64];
    f16* dst = E16 + (size_t)(row0 + r) * KPAD + col0 + half * 64;
#pragma unroll
    for (int i = 0; i < 8; ++i)
        *(uint4*)(dst + i * 8) = *(const uint4*)(src + i * 8);
}

// ---------------------------------------------------------------------------
// rowpass: c[b] = 1/(12288 * dot(E[b,:], r)), Sout[k] += E[b,k]*c[b].
// lane owns a fixed 16-col slice -> column accumulator lives in VGPRs.
__global__ __launch_bounds__(256)
void rowpass_k(const f16* __restrict__ E16, const float* __restrict__ Sin,
               float* __restrict__ Sout) {
    __shared__ float rl[KPAD];
    __shared__ float cols4[4][KPAD];
    int tid = threadIdx.x;
    for (int n = tid; n < KPAD; n += 256) {
        float s = Sin[n];
        rl[n] = (n < KDIM) ? 1.0f / (1000.0f * s) : 0.0f;
    }
    __syncthreads();
    int wave = tid >> 6, lane = tid & 63;
    int n0 = lane * 16;
    float rv[16];
#pragma unroll
    for (int i = 0; i < 16; ++i) rv[i] = rl[n0 + i];
    float ca[16];
#pragma unroll
    for (int i = 0; i < 16; ++i) ca[i] = 0.f;
    int rowbase = blockIdx.x * 16 + wave * 4;
    for (int j = 0; j < 4; ++j) {
        const f16* er = E16 + (size_t)(rowbase + j) * KPAD + n0;
        f16x8 e0 = *(const f16x8*)er;
        f16x8 e1 = *(const f16x8*)(er + 8);
        float ev[16];
#pragma unroll
        for (int i = 0; i < 8; ++i) { ev[i] = (float)e0[i]; ev[8 + i] = (float)e1[i]; }
        float p = 0.f;
#pragma unroll
        for (int i = 0; i < 16; ++i) p += ev[i] * rv[i];
        p = wsum(p);
        float c = 1.0f / (12288.0f * p);
#pragma unroll
        for (int i = 0; i < 16; ++i) ca[i] += ev[i] * c;
    }
#pragma unroll
    for (int i = 0; i < 16; ++i) {     // staggered to break bank alignment
        int idx = (i + lane) & 15;
        cols4[wave][n0 + idx] = ca[idx];
    }
    __syncthreads();
    for (int n = tid; n < KDIM; n += 256) {
        float s = cols4[0][n] + cols4[1][n] + cols4[2][n] + cols4[3][n];
        atomicAdd(&Sout[n], s);
    }
}

// ---------------------------------------------------------------------------
// out[b,:] = E[b,:]*r / dot(E[b,:], r) for rows < 4096
__global__ __launch_bounds__(256)
void out_k(const f16* __restrict__ E16, const float* __restrict__ S2,
           float* __restrict__ out) {
    __shared__ float rl[KPAD];
    int tid = threadIdx.x;
    for (int n = tid; n < KPAD; n += 256) {
        float s = S2[n];
        rl[n] = (n < KDIM) ? 1.0f / (1000.0f * s) : 0.0f;
    }
    __syncthreads();
    int wave = tid >> 6, lane = tid & 63;
    int n0 = lane * 16;
    float rv[16];
#pragma unroll
    for (int i = 0; i < 16; ++i) rv[i] = rl[n0 + i];
    int rowbase = blockIdx.x * 8 + wave * 2;
    for (int j = 0; j < 2; ++j) {
        int row = rowbase + j;
        const f16* er = E16 + (size_t)row * KPAD + n0;
        f16x8 e0 = *(const f16x8*)er;
        f16x8 e1 = *(const f16x8*)(er + 8);
        float w[16];
        float p = 0.f;
#pragma unroll
        for (int i = 0; i < 8; ++i) {
            w[i] = (float)e0[i] * rv[i];
            w[8 + i] = (float)e1[i] * rv[8 + i];
        }
#pragma unroll
        for (int i = 0; i < 16; ++i) p += w[i];
        p = wsum(p);
        float inv = 1.0f / p;
        float* orow = out + (size_t)row * KDIM;
#pragma unroll
        for (int i = 0; i < 16; i += 4) {
            int n = n0 + i;
            if (n + 3 < KDIM) {
                float4 o = { w[i] * inv, w[i + 1] * inv, w[i + 2] * inv, w[i + 3] * inv };
                *(float4*)(orow + n) = o;
            } else {
#pragma unroll
                for (int t = 0; t < 4; ++t)
                    if (n + t < KDIM) orow[n + t] = w[i + t] * inv;
            }
        }
    }
}

// ---------------------------------------------------------------------------
extern "C" void kernel_launch(void* const* d_in, const int* in_sizes, int n_in,
                              void* d_out, int out_size, void* d_ws, size_t ws_size,
                              hipStream_t stream) {
    (void)in_sizes; (void)n_in; (void)out_size; (void)ws_size;
    const float* feats = (const float*)d_in[0];   // [4096,256]
    const float* head  = (const float*)d_in[1];   // [256,1000]
    const float* queue = (const float*)d_in[2];   // [8192,256]
    float* out = (float*)d_out;                   // [4096,1000]

    char* ws = (char*)d_ws;
    f16*   A16  = (f16*)(ws + OFF_A16);
    f16*   Bf   = (f16*)(ws + OFF_BF);
    f16*   E16  = (f16*)(ws + OFF_E16);
    float* S0   = (float*)(ws + OFF_S);
    float* S1   = S0 + KPAD;
    float* S2   = S0 + 2 * KPAD;
    float* rinv = (float*)(ws + OFF_RINV);

    hipMemsetAsync(S0, 0, 3 * KPAD * sizeof(float), stream);
    hipMemsetAsync(Bf + (size_t)KDIM * DDIM, 0, (size_t)(KPAD - KDIM) * DDIM * sizeof(f16), stream);

    norm_feats_k<<<NROWS / 4, 256, 0, stream>>>(feats, queue, A16);
    rinv_k<<<DDIM, 256, 0, stream>>>(head, rinv);
    cvt_head_k<<<dim3(4, 16), 256, 0, stream>>>(head, rinv, Bf);
    gemm_exp_k<<<dim3(8, 96), 256, 0, stream>>>(A16, Bf, E16, S0);
    rowpass_k<<<NROWS / 16, 256, 0, stream>>>(E16, S0, S1);
    rowpass_k<<<NROWS / 16, 256, 0, stream>>>(E16, S1, S2);
    out_k<<<NFEAT / 8, 256, 0, stream>>>(E16, S2, out);
}

// Round 3
// 165.579 us; speedup vs baseline: 1.3971x; 1.0322x over previous
//
#include <hip/hip_runtime.h>
#include <math.h>

typedef _Float16 f16;
typedef _Float16 f16x8 __attribute__((ext_vector_type(8)));
typedef _Float16 f16x4 __attribute__((ext_vector_type(4)));
typedef float f32x4 __attribute__((ext_vector_type(4)));

#define NROWS 12288
#define NFEAT 4096
#define DDIM  256
#define KDIM  1000
#define KPAD  1024

// workspace layout (bytes)
static const size_t OFF_A16  = 0;           // 12288*256 f16 = 6,291,456
static const size_t OFF_BF   = 6291456;     // 1024*256 f16  =   524,288
static const size_t OFF_E16  = 6815744;     // 12288*1024 f16= 25,165,824
static const size_t OFF_S    = 31981568;    // 3*1024 f32

__device__ inline float wsum(float v) {
#pragma unroll
    for (int m = 32; m >= 1; m >>= 1) v += __shfl_xor(v, m, 64);
    return v;
}

// ---------------------------------------------------------------------------
// prep: [0,3072) feats/queue row norms -> A16 (4 rows/block)
//       [3072,3088) head: 16 rows/block -> rinv + transposed f16 Bf
//       [3088] zero S0/S1/S2
__global__ __launch_bounds__(256)
void prep_k(const float* __restrict__ feats, const float* __restrict__ queue,
            const float* __restrict__ head, f16* __restrict__ A16,
            f16* __restrict__ Bf, float* __restrict__ S) {
    int b = blockIdx.x, tid = threadIdx.x;
    int wave = tid >> 6, lane = tid & 63;
    if (b < 3072) {
        int row = b * 4 + wave;
        const float* src = (row < NFEAT) ? feats + (size_t)row * DDIM
                                         : queue + (size_t)(row - NFEAT) * DDIM;
        float4 v = *(const float4*)(src + lane * 4);
        float s = wsum(v.x * v.x + v.y * v.y + v.z * v.z + v.w * v.w);
        float inv = 1.0f / sqrtf(fmaxf(s, 1e-24f));
        f16x4 o = { (f16)(v.x * inv), (f16)(v.y * inv), (f16)(v.z * inv), (f16)(v.w * inv) };
        *(f16x4*)(A16 + (size_t)row * DDIM + lane * 4) = o;
    } else if (b < 3088) {
        __shared__ float rin[16];
        int kb = (b - 3072) * 16;
        for (int j = 0; j < 4; ++j) {
            int k = kb + wave * 4 + j;
            const float* hr = head + (size_t)k * KDIM;
            float s = 0.f;
            for (int n = lane; n < KDIM; n += 64) { float v = hr[n]; s += v * v; }
            s = wsum(s);
            if (lane == 0) rin[wave * 4 + j] = 1.0f / sqrtf(fmaxf(s, 1e-24f));
        }
        __syncthreads();
        float r[16];
#pragma unroll
        for (int i = 0; i < 16; ++i) r[i] = rin[i];
        for (int n = tid; n < KDIM; n += 256) {
            f16 tmp[16];
#pragma unroll
            for (int i = 0; i < 16; ++i)
                tmp[i] = (f16)(head[(size_t)(kb + i) * KDIM + n] * r[i]);
            f16* dst = Bf + (size_t)n * DDIM + kb;
            *(uint4*)(dst)     = *(const uint4*)(tmp);
            *(uint4*)(dst + 8) = *(const uint4*)(tmp + 8);
        }
    } else {
        for (int i = tid; i < 3 * KPAD; i += 256) S[i] = 0.f;
    }
}

// ---------------------------------------------------------------------------
// MFMA GEMM + exp + colsum partials + f16 E store.
// 128x128 tile, 4 waves (2x2 of 64x64), direct global fragment loads.
__global__ __launch_bounds__(256, 2)
void gemm_exp_k(const f16* __restrict__ A16, const f16* __restrict__ Bf,
                f16* __restrict__ E16, float* __restrict__ S0) {
    __shared__ f16 Es[128][136];
    int tid = threadIdx.x;
    int wave = tid >> 6, lane = tid & 63;
    int lm = lane & 15, q = lane >> 4;
    int row0 = blockIdx.y * 128, col0 = blockIdx.x * 128;
    int wm = (wave >> 1) * 64, wn = (wave & 1) * 64;
    const f16* Ab = A16 + (size_t)(row0 + wm + lm) * DDIM + q * 8;
    const f16* Bb = Bf  + (size_t)(col0 + wn + lm) * DDIM + q * 8;

    f32x4 acc[4][4];
#pragma unroll
    for (int i = 0; i < 4; ++i)
#pragma unroll
        for (int j = 0; j < 4; ++j) acc[i][j] = (f32x4){0.f, 0.f, 0.f, 0.f};

#pragma unroll
    for (int kt = 0; kt < DDIM; kt += 32) {
        f16x8 a[4], b[4];
#pragma unroll
        for (int ms = 0; ms < 4; ++ms) a[ms] = *(const f16x8*)(Ab + (size_t)ms * 16 * DDIM + kt);
#pragma unroll
        for (int ns = 0; ns < 4; ++ns) b[ns] = *(const f16x8*)(Bb + (size_t)ns * 16 * DDIM + kt);
#pragma unroll
        for (int ms = 0; ms < 4; ++ms)
#pragma unroll
            for (int ns = 0; ns < 4; ++ns)
                acc[ms][ns] = __builtin_amdgcn_mfma_f32_16x16x32_f16(a[ms], b[ns], acc[ms][ns], 0, 0, 0);
    }

    float colp[4] = {0.f, 0.f, 0.f, 0.f};
#pragma unroll
    for (int ms = 0; ms < 4; ++ms) {
#pragma unroll
        for (int ns = 0; ns < 4; ++ns) {
            int gc = col0 + wn + ns * 16 + lm;
            bool ok = gc < KDIM;
#pragma unroll
            for (int r = 0; r < 4; ++r) {
                float e = ok ? __expf(acc[ms][ns][r] * 20.0f) : 0.0f;
                colp[ns] += e;
                Es[wm + ms * 16 + q * 4 + r][wn + ns * 16 + lm] = (f16)e;
            }
        }
    }
#pragma unroll
    for (int ns = 0; ns < 4; ++ns) {
        float v = colp[ns];
        v += __shfl_xor(v, 16, 64);
        v += __shfl_xor(v, 32, 64);
        if (lane < 16) atomicAdd(&S0[col0 + wn + ns * 16 + lane], v);
    }
    __syncthreads();
    int r = tid >> 1, half = tid & 1;
    const f16* src = &Es[r][half * 64];
    f16* dst = E16 + (size_t)(row0 + r) * KPAD + col0 + half * 64;
#pragma unroll
    for (int i = 0; i < 8; ++i)
        *(uint4*)(dst + i * 8) = *(const uint4*)(src + i * 8);
}

// ---------------------------------------------------------------------------
// rowpass: c[b] = 1/(12288 * dot(E[b,:], r)), Sout[k] += E[b,k]*c[b].
// 256 blocks x 48 rows; lane owns a fixed 16-col slice (accumulator in VGPRs).
__global__ __launch_bounds__(256)
void rowpass_k(const f16* __restrict__ E16, const float* __restrict__ Sin,
               float* __restrict__ Sout) {
    __shared__ float rl[KPAD];
    __shared__ float cols4[4][KPAD];
    int tid = threadIdx.x;
    for (int n = tid; n < KPAD; n += 256) {
        float s = Sin[n];
        rl[n] = (n < KDIM) ? 1.0f / (1000.0f * s) : 0.0f;
    }
    __syncthreads();
    int wave = tid >> 6, lane = tid & 63;
    int n0 = lane * 16;
    float rv[16];
#pragma unroll
    for (int i = 0; i < 16; ++i) rv[i] = rl[n0 + i];
    float ca[16];
#pragma unroll
    for (int i = 0; i < 16; ++i) ca[i] = 0.f;
    int rowbase = blockIdx.x * 48 + wave * 12;
    for (int j = 0; j < 12; ++j) {
        const f16* er = E16 + (size_t)(rowbase + j) * KPAD + n0;
        f16x8 e0 = *(const f16x8*)er;
        f16x8 e1 = *(const f16x8*)(er + 8);
        float ev[16];
#pragma unroll
        for (int i = 0; i < 8; ++i) { ev[i] = (float)e0[i]; ev[8 + i] = (float)e1[i]; }
        float p = 0.f;
#pragma unroll
        for (int i = 0; i < 16; ++i) p += ev[i] * rv[i];
        p = wsum(p);
        float c = 1.0f / (12288.0f * p);
#pragma unroll
        for (int i = 0; i < 16; ++i) ca[i] += ev[i] * c;
    }
#pragma unroll
    for (int i = 0; i < 16; ++i) {
        int idx = (i + lane) & 15;
        cols4[wave][n0 + idx] = ca[idx];
    }
    __syncthreads();
    for (int n = tid; n < KDIM; n += 256) {
        float s = cols4[0][n] + cols4[1][n] + cols4[2][n] + cols4[3][n];
        atomicAdd(&Sout[n], s);
    }
}

// ---------------------------------------------------------------------------
// out[b,:] = E[b,:]*r / dot(E[b,:], r) for rows < 4096
__global__ __launch_bounds__(256)
void out_k(const f16* __restrict__ E16, const float* __restrict__ S2,
           float* __restrict__ out) {
    __shared__ float rl[KPAD];
    int tid = threadIdx.x;
    for (int n = tid; n < KPAD; n += 256) {
        float s = S2[n];
        rl[n] = (n < KDIM) ? 1.0f / (1000.0f * s) : 0.0f;
    }
    __syncthreads();
    int wave = tid >> 6, lane = tid & 63;
    int n0 = lane * 16;
    float rv[16];
#pragma unroll
    for (int i = 0; i < 16; ++i) rv[i] = rl[n0 + i];
    int rowbase = blockIdx.x * 8 + wave * 2;
    for (int j = 0; j < 2; ++j) {
        int row = rowbase + j;
        const f16* er = E16 + (size_t)row * KPAD + n0;
        f16x8 e0 = *(const f16x8*)er;
        f16x8 e1 = *(const f16x8*)(er + 8);
        float w[16];
        float p = 0.f;
#pragma unroll
        for (int i = 0; i < 8; ++i) {
            w[i] = (float)e0[i] * rv[i];
            w[8 + i] = (float)e1[i] * rv[8 + i];
        }
#pragma unroll
        for (int i = 0; i < 16; ++i) p += w[i];
        p = wsum(p);
        float inv = 1.0f / p;
        float* orow = out + (size_t)row * KDIM;
#pragma unroll
        for (int i = 0; i < 16; i += 4) {
            int n = n0 + i;
            if (n + 3 < KDIM) {
                float4 o = { w[i] * inv, w[i + 1] * inv, w[i + 2] * inv, w[i + 3] * inv };
                *(float4*)(orow + n) = o;
            } else {
#pragma unroll
                for (int t = 0; t < 4; ++t)
                    if (n + t < KDIM) orow[n + t] = w[i + t] * inv;
            }
        }
    }
}

// ---------------------------------------------------------------------------
extern "C" void kernel_launch(void* const* d_in, const int* in_sizes, int n_in,
                              void* d_out, int out_size, void* d_ws, size_t ws_size,
                              hipStream_t stream) {
    (void)in_sizes; (void)n_in; (void)out_size; (void)ws_size;
    const float* feats = (const float*)d_in[0];   // [4096,256]
    const float* head  = (const float*)d_in[1];   // [256,1000]
    const float* queue = (const float*)d_in[2];   // [8192,256]
    float* out = (float*)d_out;                   // [4096,1000]

    char* ws = (char*)d_ws;
    f16*   A16  = (f16*)(ws + OFF_A16);
    f16*   Bf   = (f16*)(ws + OFF_BF);
    f16*   E16  = (f16*)(ws + OFF_E16);
    float* S0   = (float*)(ws + OFF_S);
    float* S1   = S0 + KPAD;
    float* S2   = S0 + 2 * KPAD;

    prep_k<<<3089, 256, 0, stream>>>(feats, queue, head, A16, Bf, S0);
    gemm_exp_k<<<dim3(8, 96), 256, 0, stream>>>(A16, Bf, E16, S0);
    rowpass_k<<<256, 256, 0, stream>>>(E16, S0, S1);
    rowpass_k<<<256, 256, 0, stream>>>(E16, S1, S2);
    out_k<<<NFEAT / 8, 256, 0, stream>>>(E16, S2, out);
}